// Round 1
// baseline (176.366 us; speedup 1.0000x reference)
//
#include <hip/hip_runtime.h>

typedef float f32x4 __attribute__((ext_vector_type(4)));
typedef short short8 __attribute__((ext_vector_type(8)));
typedef short short4_t __attribute__((ext_vector_type(4)));

#define GLOAD_LDS16(gp, lp) \
  __builtin_amdgcn_global_load_lds((const __attribute__((address_space(1))) void*)(gp), \
                                   (__attribute__((address_space(3))) void*)(lp), 16, 0, 0)

__device__ __forceinline__ short f2bf(float f){
  unsigned u = __builtin_bit_cast(unsigned, f);
  u += 0x7fffu + ((u >> 16) & 1u);   // RNE, no NaN inputs here
  return (short)(u >> 16);
}

// ---------------- fp32 -> bf16 convert (vectorized) ----------------
__global__ void cvt_kernel(const float* __restrict__ x, short* __restrict__ xb, int n4){
  for (int i = blockIdx.x*blockDim.x + threadIdx.x; i < n4; i += gridDim.x*blockDim.x){
    f32x4 v = ((const f32x4*)x)[i];
    short4_t s;
    s[0]=f2bf(v[0]); s[1]=f2bf(v[1]); s[2]=f2bf(v[2]); s[3]=f2bf(v[3]);
    ((short4_t*)xb)[i] = s;
  }
}

// ------------- transpose+convert: w[K][N] fp32 -> wT[N][K] bf16 -------------
__global__ __launch_bounds__(256) void transpose_cvt_kernel(const float* __restrict__ w,
                                                            short* __restrict__ wT,
                                                            int K, int N){
  __shared__ float tile[32][33];
  int bn = blockIdx.x*32, bk = blockIdx.y*32;
  int tx = threadIdx.x & 31, ty = threadIdx.x >> 5;   // 256 threads: ty 0..7
  #pragma unroll
  for (int r=ty; r<32; r+=8) tile[r][tx] = w[(size_t)(bk+r)*N + bn + tx];
  __syncthreads();
  #pragma unroll
  for (int r=ty; r<32; r+=8) wT[(size_t)(bn+r)*K + bk + tx] = f2bf(tile[tx][r]);
}

// ---------------- 128x128 bf16 GEMM: C = A[M][K] * Bt[N][K]^T ----------------
// 256 threads = 4 waves (2x2), each wave 64x64 via 4x4 frags of 16x16x32.
// LDS tiles [128][64] bf16, linear for global_load_lds; XOR-swizzle applied to
// the GLOBAL source k-unit (Rule 21) and re-applied on ds_read.
// MODE 0: write fp32 C.  MODE 1: QKV epilogue -> q(prescaled)/k [bh][t][64], v^T [bh][64][t].
template<int MODE>
__global__ __launch_bounds__(256) void gemm128_kernel(
    const short* __restrict__ A, const short* __restrict__ Bt,
    float* __restrict__ Cf, short* __restrict__ qb_, short* __restrict__ kb_,
    short* __restrict__ vtb, int M, int N, int K)
{
  __shared__ short a_lds[128*64];
  __shared__ short b_lds[128*64];
  const int tid = threadIdx.x;
  const int lane = tid & 63;
  const int l15 = lane & 15, lg = lane >> 4;
  const int w  = tid >> 6;
  const int wr = w >> 1, wc = w & 1;
  const int m0 = blockIdx.x * 128, n0 = blockIdx.y * 128;

  f32x4 acc[4][4];
  #pragma unroll
  for (int i=0;i<4;i++)
    #pragma unroll
    for (int j=0;j<4;j++) acc[i][j] = (f32x4){0.f,0.f,0.f,0.f};

  for (int kt = 0; kt < K; kt += 64){
    __syncthreads();
    #pragma unroll
    for (int i=0;i<4;i++){
      int u = i*256 + tid;
      int row = u >> 3, cu = u & 7;
      int kl = ((cu ^ (row & 7)) << 3);
      GLOAD_LDS16(A + (size_t)(m0+row)*K + kt + kl, a_lds + (size_t)(i*256 + (tid & ~63))*8);
    }
    #pragma unroll
    for (int i=0;i<4;i++){
      int u = i*256 + tid;
      int row = u >> 3, cu = u & 7;
      int kl = ((cu ^ (row & 7)) << 3);
      GLOAD_LDS16(Bt + (size_t)(n0+row)*K + kt + kl, b_lds + (size_t)(i*256 + (tid & ~63))*8);
    }
    asm volatile("s_waitcnt vmcnt(0)" ::: "memory");
    __syncthreads();

    #pragma unroll
    for (int kk=0;kk<2;kk++){
      short8 af[4], bfr[4];
      #pragma unroll
      for (int mi=0;mi<4;mi++){
        int row = wr*64 + mi*16 + l15;
        int uu = ((kk*4 + lg) ^ (row & 7));
        af[mi] = *(const short8*)&a_lds[row*64 + uu*8];
      }
      #pragma unroll
      for (int ni=0;ni<4;ni++){
        int row = wc*64 + ni*16 + l15;
        int uu = ((kk*4 + lg) ^ (row & 7));
        bfr[ni] = *(const short8*)&b_lds[row*64 + uu*8];
      }
      #pragma unroll
      for (int mi=0;mi<4;mi++)
        #pragma unroll
        for (int ni=0;ni<4;ni++)
          acc[mi][ni] = __builtin_amdgcn_mfma_f32_16x16x32_bf16(af[mi], bfr[ni], acc[mi][ni], 0,0,0);
    }
  }

  // epilogue: D layout col = lane&15, row = (lane>>4)*4 + r  [verified m89/m91]
  #pragma unroll
  for (int mi=0;mi<4;mi++){
    #pragma unroll
    for (int ni=0;ni<4;ni++){
      int col = n0 + wc*64 + ni*16 + l15;
      #pragma unroll
      for (int r=0;r<4;r++){
        int rowg = m0 + wr*64 + mi*16 + lg*4 + r;
        float v = acc[mi][ni][r];
        if (MODE == 0){
          Cf[(size_t)rowg*N + col] = v;
        } else {
          int three = col >> 10, hh = (col >> 6) & 15, e = col & 63;
          int bb = rowg >> 11, t = rowg & 2047;
          int bh = bb*16 + hh;
          if (three == 0)      qb_[((size_t)bh*2048 + t)*64 + e] = f2bf(v * 0.125f); // pre-scale Q by 1/sqrt(64)
          else if (three == 1) kb_[((size_t)bh*2048 + t)*64 + e] = f2bf(v);
          else                 vtb[((size_t)bh*64 + e)*2048 + t] = f2bf(v);          // V transposed
        }
      }
    }
  }
}

// ---------------- causal flash attention ----------------
// grid = bh(32) * qblocks(32); 256 threads = 4 waves, each wave owns 16 q-rows.
// Q pre-scaled; K [bh][t][64]; V^T [bh][64][t]. KVBLK=64.
__global__ __launch_bounds__(256) void attn_kernel(
    const short* __restrict__ q, const short* __restrict__ kbuf,
    const short* __restrict__ vt, short* __restrict__ ob)
{
  __shared__ short k_lds[64*64];
  __shared__ short v_lds[64*64];          // [e][kv] (V already transposed in global)
  __shared__ short p_lds[4*16*72];        // per-wave P tile, stride 72 (alignment + bank spread)

  const int tid = threadIdx.x, lane = tid & 63, w = tid >> 6;
  const int l15 = lane & 15, lg = lane >> 4;
  const int qb = blockIdx.x & 31, bh = blockIdx.x >> 5;
  const int q0 = qb * 64;

  const short* qg = q + ((size_t)bh*2048 + q0 + w*16 + l15)*64;
  short8 qf[2];
  qf[0] = *(const short8*)(qg + lg*8);
  qf[1] = *(const short8*)(qg + 32 + lg*8);

  f32x4 o_acc[4];
  #pragma unroll
  for (int ct=0;ct<4;ct++) o_acc[ct] = (f32x4){0.f,0.f,0.f,0.f};
  float mreg[4], lreg[4];
  #pragma unroll
  for (int r=0;r<4;r++){ mreg[r] = -1e30f; lreg[r] = 0.f; }

  const short* kg = kbuf + (size_t)bh*2048*64;
  const short* vg = vt   + (size_t)bh*64*2048;
  short* pw_lds = p_lds + w*16*72;

  for (int kb = 0; kb <= qb; kb++){
    int kv0 = kb*64;
    __syncthreads();
    #pragma unroll
    for (int i=0;i<2;i++){
      int u = i*256 + tid;
      int row = u >> 3, cu = u & 7;
      int kl = ((cu ^ (row & 7)) << 3);
      GLOAD_LDS16(kg + (size_t)(kv0+row)*64 + kl, k_lds + (i*256 + (tid & ~63))*8);
    }
    #pragma unroll
    for (int i=0;i<2;i++){
      int u = i*256 + tid;
      int row = u >> 3, cu = u & 7;
      int kl = ((cu ^ (row & 7)) << 3);
      GLOAD_LDS16(vg + (size_t)row*2048 + kv0 + kl, v_lds + (i*256 + (tid & ~63))*8);
    }
    asm volatile("s_waitcnt vmcnt(0)" ::: "memory");
    __syncthreads();

    // S = Q K^T (Q pre-scaled). D rows = q-rows (lg*4+r), cols = kv (ct*16+l15).
    f32x4 s[4];
    #pragma unroll
    for (int ct=0;ct<4;ct++) s[ct] = (f32x4){0.f,0.f,0.f,0.f};
    #pragma unroll
    for (int kk=0;kk<2;kk++){
      #pragma unroll
      for (int ct=0;ct<4;ct++){
        int row = ct*16 + l15;
        int uu = ((kk*4 + lg) ^ (row & 7));
        short8 kf = *(const short8*)&k_lds[row*64 + uu*8];
        s[ct] = __builtin_amdgcn_mfma_f32_16x16x32_bf16(qf[kk], kf, s[ct], 0,0,0);
      }
    }

    if (kb == qb){
      int lrow = w*16 + lg*4;
      #pragma unroll
      for (int ct=0;ct<4;ct++){
        int lcol = ct*16 + l15;
        #pragma unroll
        for (int r=0;r<4;r++)
          if (lcol > lrow + r) s[ct][r] = -1e30f;
      }
    }

    // online softmax (fp32). Row spread across 16 lanes (col=lane&15) x 4 ct.
    float mnew[4], alpha[4];
    #pragma unroll
    for (int r=0;r<4;r++){
      float mx = fmaxf(fmaxf(s[0][r], s[1][r]), fmaxf(s[2][r], s[3][r]));
      mx = fmaxf(mx, __shfl_xor(mx, 1));
      mx = fmaxf(mx, __shfl_xor(mx, 2));
      mx = fmaxf(mx, __shfl_xor(mx, 4));
      mx = fmaxf(mx, __shfl_xor(mx, 8));
      mnew[r] = fmaxf(mreg[r], mx);
      alpha[r] = __expf(mreg[r] - mnew[r]);
      mreg[r] = mnew[r];
    }
    f32x4 p[4];
    #pragma unroll
    for (int ct=0;ct<4;ct++)
      #pragma unroll
      for (int r=0;r<4;r++)
        p[ct][r] = __expf(s[ct][r] - mnew[r]);
    #pragma unroll
    for (int r=0;r<4;r++){
      float sum = p[0][r]+p[1][r]+p[2][r]+p[3][r];
      sum += __shfl_xor(sum,1); sum += __shfl_xor(sum,2);
      sum += __shfl_xor(sum,4); sum += __shfl_xor(sum,8);
      lreg[r] = lreg[r]*alpha[r] + sum;
      #pragma unroll
      for (int ct=0;ct<4;ct++) o_acc[ct][r] *= alpha[r];
    }

    // P -> per-wave LDS (bf16), then PV MFMA. Wave-private buffer: order via waitcnt.
    #pragma unroll
    for (int ct=0;ct<4;ct++)
      #pragma unroll
      for (int r=0;r<4;r++)
        pw_lds[(lg*4 + r)*72 + ct*16 + l15] = f2bf(p[ct][r]);
    asm volatile("s_waitcnt lgkmcnt(0)" ::: "memory");

    #pragma unroll
    for (int kh=0;kh<2;kh++){
      short8 pa = *(const short8*)&pw_lds[l15*72 + kh*32 + lg*8];
      #pragma unroll
      for (int ct=0;ct<4;ct++){
        int row = ct*16 + l15;
        int uu = ((kh*4 + lg) ^ (row & 7));
        short8 vf = *(const short8*)&v_lds[row*64 + uu*8];
        o_acc[ct] = __builtin_amdgcn_mfma_f32_16x16x32_bf16(pa, vf, o_acc[ct], 0,0,0);
      }
    }
  }

  // normalize + write O as bf16 row-major [b*t][h*64+e]
  int bb = bh >> 4, hh = bh & 15;
  #pragma unroll
  for (int r=0;r<4;r++){
    float inv = 1.0f / lreg[r];
    int t = q0 + w*16 + lg*4 + r;
    size_t base = ((size_t)(bb*2048 + t))*1024 + (size_t)hh*64;
    #pragma unroll
    for (int ct=0;ct<4;ct++)
      ob[base + ct*16 + l15] = f2bf(o_acc[ct][r] * inv);
  }
}

extern "C" void kernel_launch(void* const* d_in, const int* in_sizes, int n_in,
                              void* d_out, int out_size, void* d_ws, size_t ws_size,
                              hipStream_t stream) {
  const float* x     = (const float*)d_in[0];   // [2,2048,1024]
  const float* w_qkv = (const float*)d_in[1];   // [1024,3072]
  const float* w_out = (const float*)d_in[2];   // [1024,1024]
  float* out = (float*)d_out;                   // [2,2048,1024] fp32

  char* ws = (char*)d_ws;
  short* xb    = (short*)(ws);                    // 8 MB  [4096][1024] bf16
  short* wqkvT = (short*)(ws + (8u  << 20));      // 6 MB  [3072][1024] bf16
  short* woutT = (short*)(ws + (14u << 20));      // 2 MB  [1024][1024] bf16
  short* qbuf  = (short*)(ws + (16u << 20));      // 8 MB  [32][2048][64] bf16 (prescaled)
  short* kbuf  = (short*)(ws + (24u << 20));      // 8 MB  [32][2048][64] bf16
  short* vtbuf = (short*)(ws + (32u << 20));      // 8 MB  [32][64][2048] bf16 (V^T)
  short* obuf  = (short*)(ws + (40u << 20));      // 8 MB  [4096][1024] bf16

  cvt_kernel<<<2048, 256, 0, stream>>>(x, xb, (4096*1024)/4);
  transpose_cvt_kernel<<<dim3(96,32), 256, 0, stream>>>(w_qkv, wqkvT, 1024, 3072);
  transpose_cvt_kernel<<<dim3(32,32), 256, 0, stream>>>(w_out, woutT, 1024, 1024);

  gemm128_kernel<1><<<dim3(32,24), 256, 0, stream>>>(xb, wqkvT, nullptr,
                                                     qbuf, kbuf, vtbuf, 4096, 3072, 1024);
  attn_kernel<<<dim3(1024), 256, 0, stream>>>(qbuf, kbuf, vtbuf, obuf);
  gemm128_kernel<0><<<dim3(32,8), 256, 0, stream>>>(obuf, woutT, out,
                                                    nullptr, nullptr, nullptr, 4096, 1024, 1024);
}